// Round 9
// baseline (650.959 us; speedup 1.0000x reference)
//
#include <hip/hip_runtime.h>
#include <hip/hip_fp16.h>
#include <cstdint>

#define N_NODES 50000
#define N_EDGES 800000
#define IN_FEATS 128
#define HID 64
#define HEADS 3
#define NUM_CLASSES 8
#define ATTN_SLOPE 0.2f
#define ACT_SLOPE 0.01f

// XCD-localized CSR build: 8 dst-range groups, blockIdx%8 -> XCD round-robin.
#define NGRP 8
#define GRP_NODES 6250          // N_NODES / 8
#define NCHUNK 128
#define CHUNK 6250              // ceil(N_EDGES / NCHUNK)

typedef _Float16 half8 __attribute__((ext_vector_type(8)));
typedef float f32x4 __attribute__((ext_vector_type(4)));

__device__ __forceinline__ float lrelu(float x, float s) { return x > 0.f ? x : s * x; }

// ---------- CSR build (once per call; edges are layer-invariant) ----------
__global__ __launch_bounds__(256) void k_deg(const int* __restrict__ dst, int* __restrict__ deg, int E) {
    int grp = blockIdx.x & (NGRP - 1);
    int chunk = blockIdx.x >> 3;
    int lo = grp * GRP_NODES, hi = lo + GRP_NODES;
    int s = chunk * CHUNK, e = min(E, s + CHUNK);
    for (int i = s + (int)threadIdx.x; i < e; i += 256) {
        int d = dst[i];
        if (d >= lo && d < hi) atomicAdd(&deg[d], 1);
    }
}

__global__ __launch_bounds__(256) void k_scan1(const int* __restrict__ deg, int* __restrict__ off,
                                               int* __restrict__ bsum, int n) {
    __shared__ int wtot[4];
    int tid = threadIdx.x;
    int lane = tid & 63, wid = tid >> 6;
    int base = blockIdx.x * 2048 + tid * 8;
    int v[8];
    if (base + 8 <= n) {
        int4 a = *(const int4*)&deg[base];
        int4 b = *(const int4*)&deg[base + 4];
        v[0] = a.x; v[1] = a.y; v[2] = a.z; v[3] = a.w;
        v[4] = b.x; v[5] = b.y; v[6] = b.z; v[7] = b.w;
    } else {
#pragma unroll
        for (int j = 0; j < 8; ++j) v[j] = (base + j < n) ? deg[base + j] : 0;
    }
    int s[8];
    s[0] = v[0];
#pragma unroll
    for (int j = 1; j < 8; ++j) s[j] = s[j - 1] + v[j];
    int t = s[7];
    int incl = t;
    for (int o = 1; o < 64; o <<= 1) {
        int u = __shfl_up(incl, o);
        if (lane >= o) incl += u;
    }
    int excl = incl - t;
    if (lane == 63) wtot[wid] = incl;
    __syncthreads();
    int wprefix = 0;
    for (int w = 0; w < wid; ++w) wprefix += wtot[w];
    int base_off = wprefix + excl;
#pragma unroll
    for (int j = 0; j < 8; ++j)
        if (base + j < n) off[base + j] = base_off + s[j] - v[j];
    if (tid == 0) bsum[blockIdx.x] = wtot[0] + wtot[1] + wtot[2] + wtot[3];
}

__global__ __launch_bounds__(64) void k_scan2(int* __restrict__ bsum, int nb) {
    int tid = threadIdx.x;
    int v = (tid < nb) ? bsum[tid] : 0;
    int incl = v;
    for (int o = 1; o < 64; o <<= 1) {
        int u = __shfl_up(incl, o);
        if (tid >= o) incl += u;
    }
    if (tid < nb) bsum[tid] = incl - v;   // exclusive
}

__global__ __launch_bounds__(256) void k_scan3(int* __restrict__ off, const int* __restrict__ bsum,
                                               int n, int E) {
    int i = blockIdx.x * blockDim.x + threadIdx.x;
    if (i < n) off[i] += bsum[i >> 11];
    if (i == 0) off[n] = E;
}

__global__ __launch_bounds__(256) void k_fill(const int* __restrict__ src, const int* __restrict__ dst,
                                              const int* __restrict__ off, int* __restrict__ cur,
                                              int* __restrict__ ssrc, int E) {
    int grp = blockIdx.x & (NGRP - 1);
    int chunk = blockIdx.x >> 3;
    int lo = grp * GRP_NODES, hi = lo + GRP_NODES;
    int s = chunk * CHUNK, e = min(E, s + CHUNK);
    for (int i = s + (int)threadIdx.x; i < e; i += 256) {
        int d = dst[i];
        if (d >= lo && d < hi) {
            int p = atomicAdd(&cur[d], 1);
            ssrc[off[d] + p] = src[i];
        }
    }
}

// ---------- one-time fp16 casts ----------
__global__ __launch_bounds__(256) void k_xcast(const float* __restrict__ x, _Float16* __restrict__ xh, int n8) {
    int i = blockIdx.x * blockDim.x + threadIdx.x;
    if (i < n8) {
        float4 a = *(const float4*)&x[i * 8];
        float4 b = *(const float4*)&x[i * 8 + 4];
        _Float16 v[8] = {(_Float16)a.x, (_Float16)a.y, (_Float16)a.z, (_Float16)a.w,
                         (_Float16)b.x, (_Float16)b.y, (_Float16)b.z, (_Float16)b.w};
        *(uint4*)&xh[i * 8] = *(uint4*)v;
    }
}

// W [din][192] fp32 -> Wt [192][din] fp16, all 5 layers into one buffer
__global__ __launch_bounds__(256) void k_wcast(const float* __restrict__ W1, const float* __restrict__ W2,
                                               const float* __restrict__ W3, const float* __restrict__ W4,
                                               const float* __restrict__ W5, _Float16* __restrict__ Wt) {
    int i = blockIdx.x * blockDim.x + threadIdx.x;
    if (i >= 24576 + 4 * 12288) return;
    const float* W; int din; int idx; _Float16* out;
    if (i < 24576) { W = W1; din = 128; idx = i; out = Wt; }
    else {
        int j = i - 24576; int l = j / 12288; idx = j % 12288;
        W = (l == 0) ? W2 : (l == 1) ? W3 : (l == 2) ? W4 : W5;
        din = 64;
        out = Wt + 24576 + l * 12288;
    }
    int col = idx / din, k = idx % din;
    out[idx] = (_Float16)W[k * 192 + col];
}

// ---------- feat = h @ W via MFMA, all 3 heads, 64-row tiles ----------
// Block: 384 threads (6 waves), tile 64 rows x 192 cols. Wave w: head = w>>1,
// row-half = w&1 -> 32 rows x 64 cols per wave. 782 blocks, 37KB LDS ->
// 4 blocks/CU (vs 391 blocks / 46KB before): more resident blocks to hide
// the serial stage->sync->mfma dependency.
__global__ __launch_bounds__(384) void k_gemm(const _Float16* __restrict__ h, const _Float16* __restrict__ Wt,
                                              const float* __restrict__ al, const float* __restrict__ ar,
                                              _Float16* __restrict__ feat,
                                              float* __restrict__ el, float* __restrict__ er,
                                              int N, int din) {
    __shared__ __align__(16) _Float16 Hl[64 * 72];
    __shared__ __align__(16) _Float16 Wl[192 * 72];
    const int LD = 72;
    int tid = threadIdx.x;
    int row0 = blockIdx.x * 64;
    int wid = tid >> 6, lane = tid & 63;
    int head = wid >> 1, rh = wid & 1;
    int c0 = head * 64;
    int l15 = lane & 15;
    int koff = (lane >> 4) * 8;
    int wr0 = rh * 32;

    f32x4 acc[2][4] = {};

    for (int k0 = 0; k0 < din; k0 += 64) {
        if (k0 > 0) __syncthreads();
        // stage W^T chunk [192][64]
        for (int i = tid; i < 192 * 8; i += 384) {
            int col = i >> 3, c8 = i & 7;
            *(uint4*)&Wl[col * LD + c8 * 8] = *(const uint4*)&Wt[(size_t)col * din + k0 + c8 * 8];
        }
        // stage H chunk [64][64]
        for (int i = tid; i < 64 * 8; i += 384) {
            int r = i >> 3, c8 = i & 7;
            int row = row0 + r;
            uint4 v = make_uint4(0, 0, 0, 0);
            if (row < N) v = *(const uint4*)&h[(size_t)row * din + k0 + c8 * 8];
            *(uint4*)&Hl[r * LD + c8 * 8] = v;
        }
        __syncthreads();

#pragma unroll
        for (int kb = 0; kb < 2; ++kb) {
            int kbase = kb * 32 + koff;
            half8 b0 = *(half8*)&Wl[(c0 + l15) * LD + kbase];
            half8 b1 = *(half8*)&Wl[(c0 + 16 + l15) * LD + kbase];
            half8 b2 = *(half8*)&Wl[(c0 + 32 + l15) * LD + kbase];
            half8 b3 = *(half8*)&Wl[(c0 + 48 + l15) * LD + kbase];
#pragma unroll
            for (int rt = 0; rt < 2; ++rt) {
                half8 a = *(half8*)&Hl[(wr0 + rt * 16 + l15) * LD + kbase];
                acc[rt][0] = __builtin_amdgcn_mfma_f32_16x16x32_f16(a, b0, acc[rt][0], 0, 0, 0);
                acc[rt][1] = __builtin_amdgcn_mfma_f32_16x16x32_f16(a, b1, acc[rt][1], 0, 0, 0);
                acc[rt][2] = __builtin_amdgcn_mfma_f32_16x16x32_f16(a, b2, acc[rt][2], 0, 0, 0);
                acc[rt][3] = __builtin_amdgcn_mfma_f32_16x16x32_f16(a, b3, acc[rt][3], 0, 0, 0);
            }
        }
    }

    float alv[4], arv[4];
#pragma unroll
    for (int ct = 0; ct < 4; ++ct) {
        alv[ct] = al[c0 + ct * 16 + l15];
        arv[ct] = ar[c0 + ct * 16 + l15];
    }

#pragma unroll
    for (int rt = 0; rt < 2; ++rt) {
#pragma unroll
        for (int r = 0; r < 4; ++r) {
            int row = row0 + wr0 + rt * 16 + (lane >> 4) * 4 + r;
            bool ok = (row < N);
            float c0v = acc[rt][0][r], c1v = acc[rt][1][r], c2v = acc[rt][2][r], c3v = acc[rt][3][r];
            if (ok) {
                size_t base = (size_t)row * 192 + c0;
                feat[base + l15]      = (_Float16)c0v;
                feat[base + 16 + l15] = (_Float16)c1v;
                feat[base + 32 + l15] = (_Float16)c2v;
                feat[base + 48 + l15] = (_Float16)c3v;
            }
            float pl = c0v * alv[0] + c1v * alv[1] + c2v * alv[2] + c3v * alv[3];
            float pr = c0v * arv[0] + c1v * arv[1] + c2v * arv[2] + c3v * arv[3];
            for (int o = 1; o < 16; o <<= 1) {
                pl += __shfl_xor(pl, o);
                pr += __shfl_xor(pr, o);
            }
            if (ok && l15 == 0) {
                el[row * HEADS + head] = pl;
                er[row * HEADS + head] = pr;
            }
        }
    }
}

// ---------- edge softmax + aggregate + bias + leakyrelu + head-mean ----------
// Persistent one-wave blocks (grid-stride over nodes) + 8-edge gather unroll:
// 24 independent gathers in flight per wave.
__global__ __launch_bounds__(64) void k_agg(const int* __restrict__ off, const int* __restrict__ ssrc,
                                            const float* __restrict__ el, const float* __restrict__ er,
                                            const __half* __restrict__ feat, const float* __restrict__ b,
                                            __half* __restrict__ hout, int N) {
    __shared__ float4 ebuf[64];
    int lane = threadIdx.x;
    for (int wid = blockIdx.x; wid < N; wid += gridDim.x) {
    int start = off[wid], end = off[wid + 1];
    int cnt = end - start;
    float er0 = er[wid * HEADS + 0];
    float er1 = er[wid * HEADS + 1];
    float er2 = er[wid * HEADS + 2];
    float acc0 = 0.f, acc1 = 0.f, acc2 = 0.f;
    float den0 = 0.f, den1 = 0.f, den2 = 0.f;

#define GATHER1(vv)                                                                  \
    {                                                                                \
        const __half* fr = feat + (size_t)__float_as_int((vv).x) * 192 + lane;       \
        acc0 += (vv).y * __half2float(fr[0]);                                        \
        acc1 += (vv).z * __half2float(fr[64]);                                       \
        acc2 += (vv).w * __half2float(fr[128]);                                      \
    }

    if (cnt <= 64) {
        int s0 = 0;
        float ea = -3.4e38f, eb = -3.4e38f, ec = -3.4e38f;
        if (lane < cnt) {
            s0 = ssrc[start + lane];
            ea = lrelu(el[s0 * HEADS + 0] + er0, ATTN_SLOPE);
            eb = lrelu(el[s0 * HEADS + 1] + er1, ATTN_SLOPE);
            ec = lrelu(el[s0 * HEADS + 2] + er2, ATTN_SLOPE);
        }
        float ma = ea, mb = eb, mc = ec;
        for (int o = 32; o > 0; o >>= 1) {
            ma = fmaxf(ma, __shfl_xor(ma, o));
            mb = fmaxf(mb, __shfl_xor(mb, o));
            mc = fmaxf(mc, __shfl_xor(mc, o));
        }
        float xa = (lane < cnt) ? __expf(ea - ma) : 0.f;
        float xb = (lane < cnt) ? __expf(eb - mb) : 0.f;
        float xc = (lane < cnt) ? __expf(ec - mc) : 0.f;
        float da = xa, db = xb, dc = xc;
        for (int o = 32; o > 0; o >>= 1) {
            da += __shfl_xor(da, o);
            db += __shfl_xor(db, o);
            dc += __shfl_xor(dc, o);
        }
        den0 = da; den1 = db; den2 = dc;
        ebuf[lane] = make_float4(__int_as_float(s0), xa, xb, xc);
        int t = 0;
        for (; t + 8 <= cnt; t += 8) {
            float4 v0 = ebuf[t + 0];
            float4 v1 = ebuf[t + 1];
            float4 v2 = ebuf[t + 2];
            float4 v3 = ebuf[t + 3];
            float4 v4 = ebuf[t + 4];
            float4 v5 = ebuf[t + 5];
            float4 v6 = ebuf[t + 6];
            float4 v7 = ebuf[t + 7];
            GATHER1(v0); GATHER1(v1); GATHER1(v2); GATHER1(v3);
            GATHER1(v4); GATHER1(v5); GATHER1(v6); GATHER1(v7);
        }
        for (; t < cnt; ++t) {
            float4 v = ebuf[t];
            GATHER1(v);
        }
    } else {
        float ma = -3.4e38f, mb = -3.4e38f, mc = -3.4e38f;
        for (int j = start + lane; j < end; j += 64) {
            int s = ssrc[j];
            ma = fmaxf(ma, lrelu(el[s * HEADS + 0] + er0, ATTN_SLOPE));
            mb = fmaxf(mb, lrelu(el[s * HEADS + 1] + er1, ATTN_SLOPE));
            mc = fmaxf(mc, lrelu(el[s * HEADS + 2] + er2, ATTN_SLOPE));
        }
        for (int o = 32; o > 0; o >>= 1) {
            ma = fmaxf(ma, __shfl_xor(ma, o));
            mb = fmaxf(mb, __shfl_xor(mb, o));
            mc = fmaxf(mc, __shfl_xor(mc, o));
        }
        float da = 0.f, db = 0.f, dc = 0.f;
        for (int j0 = start; j0 < end; j0 += 64) {
            int jj = j0 + lane;
            int s0 = 0;
            float xa = 0.f, xb = 0.f, xc = 0.f;
            if (jj < end) {
                s0 = ssrc[jj];
                xa = __expf(lrelu(el[s0 * HEADS + 0] + er0, ATTN_SLOPE) - ma);
                xb = __expf(lrelu(el[s0 * HEADS + 1] + er1, ATTN_SLOPE) - mb);
                xc = __expf(lrelu(el[s0 * HEADS + 2] + er2, ATTN_SLOPE) - mc);
            }
            da += xa; db += xb; dc += xc;
            ebuf[lane] = make_float4(__int_as_float(s0), xa, xb, xc);
            int c = min(64, end - j0);
            int t = 0;
            for (; t + 8 <= c; t += 8) {
                float4 v0 = ebuf[t + 0];
                float4 v1 = ebuf[t + 1];
                float4 v2 = ebuf[t + 2];
                float4 v3 = ebuf[t + 3];
                float4 v4 = ebuf[t + 4];
                float4 v5 = ebuf[t + 5];
                float4 v6 = ebuf[t + 6];
                float4 v7 = ebuf[t + 7];
                GATHER1(v0); GATHER1(v1); GATHER1(v2); GATHER1(v3);
                GATHER1(v4); GATHER1(v5); GATHER1(v6); GATHER1(v7);
            }
            for (; t < c; ++t) {
                float4 v = ebuf[t];
                GATHER1(v);
            }
        }
        for (int o = 32; o > 0; o >>= 1) {
            da += __shfl_xor(da, o);
            db += __shfl_xor(db, o);
            dc += __shfl_xor(dc, o);
        }
        den0 = da; den1 = db; den2 = dc;
    }
#undef GATHER1

    float v0 = (cnt > 0) ? acc0 / den0 : 0.f;
    float v1 = (cnt > 0) ? acc1 / den1 : 0.f;
    float v2 = (cnt > 0) ? acc2 / den2 : 0.f;
    float hsum = lrelu(v0 + b[lane], ACT_SLOPE)
               + lrelu(v1 + b[64 + lane], ACT_SLOPE)
               + lrelu(v2 + b[128 + lane], ACT_SLOPE);
    hout[wid * 64 + lane] = __float2half(hsum * (1.f / 3.f));
    }
}

// ---------- logits = h @ Wo + bo ----------
__global__ __launch_bounds__(256) void k_out(const __half* __restrict__ h, const float* __restrict__ Wo,
                                             const float* __restrict__ bo, float* __restrict__ out, int N) {
    __shared__ float Hl[32][65];
    __shared__ float Wl[64 * 8];
    int tid = threadIdx.x;
    int n0 = blockIdx.x * 32;
    for (int i = tid; i < 32 * 64; i += 256) {
        int r = i >> 6, k = i & 63;
        Hl[r][k] = (n0 + r < N) ? __half2float(h[(n0 + r) * 64 + k]) : 0.f;
    }
    for (int i = tid; i < 512; i += 256) Wl[i] = Wo[i];
    __syncthreads();
    int r = tid >> 3, c = tid & 7;
    float acc = 0.f;
    for (int k = 0; k < 64; ++k) acc += Hl[r][k] * Wl[k * 8 + c];
    int row = n0 + r;
    if (row < N) out[row * 8 + c] = acc + bo[c];
}

extern "C" void kernel_launch(void* const* d_in, const int* in_sizes, int n_in,
                              void* d_out, int out_size, void* d_ws, size_t ws_size,
                              hipStream_t stream) {
    const float* x  = (const float*)d_in[0];
    const int* src  = (const int*)d_in[1];
    const int* dst  = (const int*)d_in[2];
    const float *W[5], *b[5], *al[5], *ar[5];
    for (int l = 0; l < 5; ++l) {
        W[l]  = (const float*)d_in[3 + l * 4];
        b[l]  = (const float*)d_in[4 + l * 4];
        al[l] = (const float*)d_in[5 + l * 4];
        ar[l] = (const float*)d_in[6 + l * 4];
    }
    const float* Wo = (const float*)d_in[23];
    const float* bo = (const float*)d_in[24];
    float* out = (float*)d_out;

    char* ws = (char*)d_ws;
    auto alloc = [&](size_t bytes) {
        char* p = ws;
        ws += (bytes + 255) & ~size_t(255);
        return p;
    };
    _Float16* feat = (_Float16*)alloc(sizeof(_Float16) * (size_t)N_NODES * 192);
    float* el      = (float*)alloc(sizeof(float) * (size_t)N_NODES * HEADS);
    float* er      = (float*)alloc(sizeof(float) * (size_t)N_NODES * HEADS);
    _Float16* xh   = (_Float16*)alloc(sizeof(_Float16) * (size_t)N_NODES * IN_FEATS);
    _Float16* h0   = (_Float16*)alloc(sizeof(_Float16) * (size_t)N_NODES * 64);
    _Float16* h1   = (_Float16*)alloc(sizeof(_Float16) * (size_t)N_NODES * 64);
    _Float16* wt   = (_Float16*)alloc(sizeof(_Float16) * (24576 + 4 * 12288));
    int* deg    = (int*)alloc(sizeof(int) * N_NODES);
    int* off    = (int*)alloc(sizeof(int) * (N_NODES + 1));
    int* cur    = (int*)alloc(sizeof(int) * N_NODES);
    int* ssrc   = (int*)alloc(sizeof(int) * N_EDGES);
    int* bsum   = (int*)alloc(sizeof(int) * 64);

    const int NB = (N_NODES + 2047) / 2048;   // 25 (<=64 required by k_scan2)
    (void)hipMemsetAsync(deg, 0, sizeof(int) * N_NODES, stream);
    (void)hipMemsetAsync(cur, 0, sizeof(int) * N_NODES, stream);
    k_deg<<<NCHUNK * NGRP, 256, 0, stream>>>(dst, deg, N_EDGES);
    k_scan1<<<NB, 256, 0, stream>>>(deg, off, bsum, N_NODES);
    k_scan2<<<1, 64, 0, stream>>>(bsum, NB);
    k_scan3<<<(N_NODES + 255) / 256, 256, 0, stream>>>(off, bsum, N_NODES, N_EDGES);
    k_fill<<<NCHUNK * NGRP, 256, 0, stream>>>(src, dst, off, cur, ssrc, N_EDGES);
    k_xcast<<<(N_NODES * IN_FEATS / 8 + 255) / 256, 256, 0, stream>>>(x, xh, N_NODES * IN_FEATS / 8);
    k_wcast<<<(24576 + 4 * 12288 + 255) / 256, 256, 0, stream>>>(W[0], W[1], W[2], W[3], W[4], wt);

    const _Float16* hin = xh;
    _Float16* hbuf[2] = {h0, h1};
    const _Float16* wts[5] = {wt, wt + 24576, wt + 24576 + 12288, wt + 24576 + 2 * 12288, wt + 24576 + 3 * 12288};
    int din = IN_FEATS;
    for (int l = 0; l < 5; ++l) {
        k_gemm<<<(N_NODES + 63) / 64, 384, 0, stream>>>(hin, wts[l], al[l], ar[l], feat, el, er, N_NODES, din);
        _Float16* hn = hbuf[l & 1];
        k_agg<<<6144, 64, 0, stream>>>(off, ssrc, el, er,
                                       (const __half*)feat, b[l],
                                       (__half*)hn, N_NODES);
        hin = hn;
        din = HID;
    }
    k_out<<<(N_NODES + 31) / 32, 256, 0, stream>>>((const __half*)hin, Wo, bo, out, N_NODES);
}

// Round 10
// 514.399 us; speedup vs baseline: 1.2655x; 1.2655x over previous
//
#include <hip/hip_runtime.h>
#include <hip/hip_fp16.h>
#include <cstdint>

#define N_NODES 50000
#define N_EDGES 800000
#define IN_FEATS 128
#define HID 64
#define HEADS 3
#define NUM_CLASSES 8
#define ATTN_SLOPE 0.2f
#define ACT_SLOPE 0.01f

// XCD-localized CSR build: 8 dst-range groups, blockIdx%8 -> XCD round-robin.
#define NGRP 8
#define GRP_NODES 6250          // N_NODES / 8
#define NCHUNK 128
#define CHUNK 6250              // ceil(N_EDGES / NCHUNK)

typedef _Float16 half8 __attribute__((ext_vector_type(8)));
typedef float f32x4 __attribute__((ext_vector_type(4)));

__device__ __forceinline__ float lrelu(float x, float s) { return x > 0.f ? x : s * x; }

// ---------- CSR build (once per call; edges are layer-invariant) ----------
__global__ __launch_bounds__(256) void k_deg(const int* __restrict__ dst, int* __restrict__ deg, int E) {
    int grp = blockIdx.x & (NGRP - 1);
    int chunk = blockIdx.x >> 3;
    int lo = grp * GRP_NODES, hi = lo + GRP_NODES;
    int s = chunk * CHUNK, e = min(E, s + CHUNK);
    for (int i = s + (int)threadIdx.x; i < e; i += 256) {
        int d = dst[i];
        if (d >= lo && d < hi) atomicAdd(&deg[d], 1);
    }
}

__global__ __launch_bounds__(256) void k_scan1(const int* __restrict__ deg, int* __restrict__ off,
                                               int* __restrict__ bsum, int n) {
    __shared__ int wtot[4];
    int tid = threadIdx.x;
    int lane = tid & 63, wid = tid >> 6;
    int base = blockIdx.x * 2048 + tid * 8;
    int v[8];
    if (base + 8 <= n) {
        int4 a = *(const int4*)&deg[base];
        int4 b = *(const int4*)&deg[base + 4];
        v[0] = a.x; v[1] = a.y; v[2] = a.z; v[3] = a.w;
        v[4] = b.x; v[5] = b.y; v[6] = b.z; v[7] = b.w;
    } else {
#pragma unroll
        for (int j = 0; j < 8; ++j) v[j] = (base + j < n) ? deg[base + j] : 0;
    }
    int s[8];
    s[0] = v[0];
#pragma unroll
    for (int j = 1; j < 8; ++j) s[j] = s[j - 1] + v[j];
    int t = s[7];
    int incl = t;
    for (int o = 1; o < 64; o <<= 1) {
        int u = __shfl_up(incl, o);
        if (lane >= o) incl += u;
    }
    int excl = incl - t;
    if (lane == 63) wtot[wid] = incl;
    __syncthreads();
    int wprefix = 0;
    for (int w = 0; w < wid; ++w) wprefix += wtot[w];
    int base_off = wprefix + excl;
#pragma unroll
    for (int j = 0; j < 8; ++j)
        if (base + j < n) off[base + j] = base_off + s[j] - v[j];
    if (tid == 0) bsum[blockIdx.x] = wtot[0] + wtot[1] + wtot[2] + wtot[3];
}

__global__ __launch_bounds__(64) void k_scan2(int* __restrict__ bsum, int nb) {
    int tid = threadIdx.x;
    int v = (tid < nb) ? bsum[tid] : 0;
    int incl = v;
    for (int o = 1; o < 64; o <<= 1) {
        int u = __shfl_up(incl, o);
        if (tid >= o) incl += u;
    }
    if (tid < nb) bsum[tid] = incl - v;   // exclusive
}

__global__ __launch_bounds__(256) void k_scan3(int* __restrict__ off, const int* __restrict__ bsum,
                                               int n, int E) {
    int i = blockIdx.x * blockDim.x + threadIdx.x;
    if (i < n) off[i] += bsum[i >> 11];
    if (i == 0) off[n] = E;
}

__global__ __launch_bounds__(256) void k_fill(const int* __restrict__ src, const int* __restrict__ dst,
                                              const int* __restrict__ off, int* __restrict__ cur,
                                              int* __restrict__ ssrc, int E) {
    int grp = blockIdx.x & (NGRP - 1);
    int chunk = blockIdx.x >> 3;
    int lo = grp * GRP_NODES, hi = lo + GRP_NODES;
    int s = chunk * CHUNK, e = min(E, s + CHUNK);
    for (int i = s + (int)threadIdx.x; i < e; i += 256) {
        int d = dst[i];
        if (d >= lo && d < hi) {
            int p = atomicAdd(&cur[d], 1);
            ssrc[off[d] + p] = src[i];
        }
    }
}

// ---------- one-time fp16 casts ----------
__global__ __launch_bounds__(256) void k_xcast(const float* __restrict__ x, _Float16* __restrict__ xh, int n8) {
    int i = blockIdx.x * blockDim.x + threadIdx.x;
    if (i < n8) {
        float4 a = *(const float4*)&x[i * 8];
        float4 b = *(const float4*)&x[i * 8 + 4];
        _Float16 v[8] = {(_Float16)a.x, (_Float16)a.y, (_Float16)a.z, (_Float16)a.w,
                         (_Float16)b.x, (_Float16)b.y, (_Float16)b.z, (_Float16)b.w};
        *(uint4*)&xh[i * 8] = *(uint4*)v;
    }
}

// W [din][192] fp32 -> Wt [192][din] fp16, all 5 layers into one buffer
__global__ __launch_bounds__(256) void k_wcast(const float* __restrict__ W1, const float* __restrict__ W2,
                                               const float* __restrict__ W3, const float* __restrict__ W4,
                                               const float* __restrict__ W5, _Float16* __restrict__ Wt) {
    int i = blockIdx.x * blockDim.x + threadIdx.x;
    if (i >= 24576 + 4 * 12288) return;
    const float* W; int din; int idx; _Float16* out;
    if (i < 24576) { W = W1; din = 128; idx = i; out = Wt; }
    else {
        int j = i - 24576; int l = j / 12288; idx = j % 12288;
        W = (l == 0) ? W2 : (l == 1) ? W3 : (l == 2) ? W4 : W5;
        din = 64;
        out = Wt + 24576 + l * 12288;
    }
    int col = idx / din, k = idx % din;
    out[idx] = (_Float16)W[k * 192 + col];
}

// ---------- feat = h @ W via MFMA, LDS-FREE, fused el/er ----------
// One wave per 32-row x 64-col (one head) output tile; NO LDS, NO barriers.
// A/B fragments loaded straight from global (h, Wt are L2/L3-resident:
// 6.4-12.8MB and 24-48KB). 16B/lane loads, full ILP, waves retire
// independently -- same structure that works for k_agg. Tests the theory
// that the old stage->sync->mfma structure was latency-bound at 1.5 blk/CU.
__global__ __launch_bounds__(64) void k_gemm(const _Float16* __restrict__ h, const _Float16* __restrict__ Wt,
                                             const float* __restrict__ al, const float* __restrict__ ar,
                                             _Float16* __restrict__ feat,
                                             float* __restrict__ el, float* __restrict__ er,
                                             int N, int din) {
    int bid = blockIdx.x;
    int head = bid % 3;
    int rt0 = bid / 3;
    int row0 = rt0 * 32;
    int c0 = head * 64;
    int lane = threadIdx.x;
    int l15 = lane & 15;
    int koff = (lane >> 4) * 8;

    f32x4 acc[2][4] = {};
    int r0 = min(row0 + l15, N - 1);        // clamped A-frag rows (output guarded)
    int r1 = min(row0 + 16 + l15, N - 1);
    const _Float16* wbase = Wt + (size_t)(c0 + l15) * din + koff;
    const _Float16* hbase0 = h + (size_t)r0 * din + koff;
    const _Float16* hbase1 = h + (size_t)r1 * din + koff;

    int nkb = din >> 5;
    for (int kb = 0; kb < nkb; ++kb) {
        int kb32 = kb * 32;
        half8 b0 = *(const half8*)&wbase[kb32];
        half8 b1 = *(const half8*)&wbase[16 * din + kb32];
        half8 b2 = *(const half8*)&wbase[32 * din + kb32];
        half8 b3 = *(const half8*)&wbase[48 * din + kb32];
        half8 a0 = *(const half8*)&hbase0[kb32];
        half8 a1 = *(const half8*)&hbase1[kb32];
        acc[0][0] = __builtin_amdgcn_mfma_f32_16x16x32_f16(a0, b0, acc[0][0], 0, 0, 0);
        acc[0][1] = __builtin_amdgcn_mfma_f32_16x16x32_f16(a0, b1, acc[0][1], 0, 0, 0);
        acc[0][2] = __builtin_amdgcn_mfma_f32_16x16x32_f16(a0, b2, acc[0][2], 0, 0, 0);
        acc[0][3] = __builtin_amdgcn_mfma_f32_16x16x32_f16(a0, b3, acc[0][3], 0, 0, 0);
        acc[1][0] = __builtin_amdgcn_mfma_f32_16x16x32_f16(a1, b0, acc[1][0], 0, 0, 0);
        acc[1][1] = __builtin_amdgcn_mfma_f32_16x16x32_f16(a1, b1, acc[1][1], 0, 0, 0);
        acc[1][2] = __builtin_amdgcn_mfma_f32_16x16x32_f16(a1, b2, acc[1][2], 0, 0, 0);
        acc[1][3] = __builtin_amdgcn_mfma_f32_16x16x32_f16(a1, b3, acc[1][3], 0, 0, 0);
    }

    float alv[4], arv[4];
#pragma unroll
    for (int ct = 0; ct < 4; ++ct) {
        alv[ct] = al[c0 + ct * 16 + l15];
        arv[ct] = ar[c0 + ct * 16 + l15];
    }

#pragma unroll
    for (int rt = 0; rt < 2; ++rt) {
#pragma unroll
        for (int r = 0; r < 4; ++r) {
            int row = row0 + rt * 16 + (lane >> 4) * 4 + r;
            bool ok = (row < N);
            float c0v = acc[rt][0][r], c1v = acc[rt][1][r], c2v = acc[rt][2][r], c3v = acc[rt][3][r];
            if (ok) {
                size_t base = (size_t)row * 192 + c0;
                feat[base + l15]      = (_Float16)c0v;
                feat[base + 16 + l15] = (_Float16)c1v;
                feat[base + 32 + l15] = (_Float16)c2v;
                feat[base + 48 + l15] = (_Float16)c3v;
            }
            float pl = c0v * alv[0] + c1v * alv[1] + c2v * alv[2] + c3v * alv[3];
            float pr = c0v * arv[0] + c1v * arv[1] + c2v * arv[2] + c3v * arv[3];
            for (int o = 1; o < 16; o <<= 1) {
                pl += __shfl_xor(pl, o);
                pr += __shfl_xor(pr, o);
            }
            if (ok && l15 == 0) {
                el[row * HEADS + head] = pl;
                er[row * HEADS + head] = pr;
            }
        }
    }
}

// ---------- edge softmax + aggregate + bias + leakyrelu + head-mean ----------
// One wave per dst node, one wave per block (round-8 known-good form).
__global__ __launch_bounds__(64) void k_agg(const int* __restrict__ off, const int* __restrict__ ssrc,
                                            const float* __restrict__ el, const float* __restrict__ er,
                                            const __half* __restrict__ feat, const float* __restrict__ b,
                                            __half* __restrict__ hout, int N) {
    __shared__ float4 ebuf[64];
    int wid = blockIdx.x;
    int lane = threadIdx.x;
    if (wid >= N) return;
    int start = off[wid], end = off[wid + 1];
    int cnt = end - start;
    float er0 = er[wid * HEADS + 0];
    float er1 = er[wid * HEADS + 1];
    float er2 = er[wid * HEADS + 2];
    float acc0 = 0.f, acc1 = 0.f, acc2 = 0.f;
    float den0 = 0.f, den1 = 0.f, den2 = 0.f;

    if (cnt <= 64) {
        int s0 = 0;
        float ea = -3.4e38f, eb = -3.4e38f, ec = -3.4e38f;
        if (lane < cnt) {
            s0 = ssrc[start + lane];
            ea = lrelu(el[s0 * HEADS + 0] + er0, ATTN_SLOPE);
            eb = lrelu(el[s0 * HEADS + 1] + er1, ATTN_SLOPE);
            ec = lrelu(el[s0 * HEADS + 2] + er2, ATTN_SLOPE);
        }
        float ma = ea, mb = eb, mc = ec;
        for (int o = 32; o > 0; o >>= 1) {
            ma = fmaxf(ma, __shfl_xor(ma, o));
            mb = fmaxf(mb, __shfl_xor(mb, o));
            mc = fmaxf(mc, __shfl_xor(mc, o));
        }
        float xa = (lane < cnt) ? __expf(ea - ma) : 0.f;
        float xb = (lane < cnt) ? __expf(eb - mb) : 0.f;
        float xc = (lane < cnt) ? __expf(ec - mc) : 0.f;
        float da = xa, db = xb, dc = xc;
        for (int o = 32; o > 0; o >>= 1) {
            da += __shfl_xor(da, o);
            db += __shfl_xor(db, o);
            dc += __shfl_xor(dc, o);
        }
        den0 = da; den1 = db; den2 = dc;
        ebuf[lane] = make_float4(__int_as_float(s0), xa, xb, xc);
        int t = 0;
        for (; t + 4 <= cnt; t += 4) {
            float4 v0 = ebuf[t + 0];
            float4 v1 = ebuf[t + 1];
            float4 v2 = ebuf[t + 2];
            float4 v3 = ebuf[t + 3];
            const __half* f0 = feat + (size_t)__float_as_int(v0.x) * 192 + lane;
            const __half* f1 = feat + (size_t)__float_as_int(v1.x) * 192 + lane;
            const __half* f2 = feat + (size_t)__float_as_int(v2.x) * 192 + lane;
            const __half* f3 = feat + (size_t)__float_as_int(v3.x) * 192 + lane;
            float p00 = __half2float(f0[0]), p01 = __half2float(f0[64]), p02 = __half2float(f0[128]);
            float p10 = __half2float(f1[0]), p11 = __half2float(f1[64]), p12 = __half2float(f1[128]);
            float p20 = __half2float(f2[0]), p21 = __half2float(f2[64]), p22 = __half2float(f2[128]);
            float p30 = __half2float(f3[0]), p31 = __half2float(f3[64]), p32 = __half2float(f3[128]);
            acc0 += v0.y * p00; acc1 += v0.z * p01; acc2 += v0.w * p02;
            acc0 += v1.y * p10; acc1 += v1.z * p11; acc2 += v1.w * p12;
            acc0 += v2.y * p20; acc1 += v2.z * p21; acc2 += v2.w * p22;
            acc0 += v3.y * p30; acc1 += v3.z * p31; acc2 += v3.w * p32;
        }
        for (; t < cnt; ++t) {
            float4 v = ebuf[t];
            const __half* fr = feat + (size_t)__float_as_int(v.x) * 192 + lane;
            acc0 += v.y * __half2float(fr[0]);
            acc1 += v.z * __half2float(fr[64]);
            acc2 += v.w * __half2float(fr[128]);
        }
    } else {
        float ma = -3.4e38f, mb = -3.4e38f, mc = -3.4e38f;
        for (int j = start + lane; j < end; j += 64) {
            int s = ssrc[j];
            ma = fmaxf(ma, lrelu(el[s * HEADS + 0] + er0, ATTN_SLOPE));
            mb = fmaxf(mb, lrelu(el[s * HEADS + 1] + er1, ATTN_SLOPE));
            mc = fmaxf(mc, lrelu(el[s * HEADS + 2] + er2, ATTN_SLOPE));
        }
        for (int o = 32; o > 0; o >>= 1) {
            ma = fmaxf(ma, __shfl_xor(ma, o));
            mb = fmaxf(mb, __shfl_xor(mb, o));
            mc = fmaxf(mc, __shfl_xor(mc, o));
        }
        float da = 0.f, db = 0.f, dc = 0.f;
        for (int j0 = start; j0 < end; j0 += 64) {
            int jj = j0 + lane;
            int s0 = 0;
            float xa = 0.f, xb = 0.f, xc = 0.f;
            if (jj < end) {
                s0 = ssrc[jj];
                xa = __expf(lrelu(el[s0 * HEADS + 0] + er0, ATTN_SLOPE) - ma);
                xb = __expf(lrelu(el[s0 * HEADS + 1] + er1, ATTN_SLOPE) - mb);
                xc = __expf(lrelu(el[s0 * HEADS + 2] + er2, ATTN_SLOPE) - mc);
            }
            da += xa; db += xb; dc += xc;
            ebuf[lane] = make_float4(__int_as_float(s0), xa, xb, xc);
            int c = min(64, end - j0);
            int t = 0;
            for (; t + 4 <= c; t += 4) {
                float4 v0 = ebuf[t + 0];
                float4 v1 = ebuf[t + 1];
                float4 v2 = ebuf[t + 2];
                float4 v3 = ebuf[t + 3];
                const __half* f0 = feat + (size_t)__float_as_int(v0.x) * 192 + lane;
                const __half* f1 = feat + (size_t)__float_as_int(v1.x) * 192 + lane;
                const __half* f2 = feat + (size_t)__float_as_int(v2.x) * 192 + lane;
                const __half* f3 = feat + (size_t)__float_as_int(v3.x) * 192 + lane;
                float p00 = __half2float(f0[0]), p01 = __half2float(f0[64]), p02 = __half2float(f0[128]);
                float p10 = __half2float(f1[0]), p11 = __half2float(f1[64]), p12 = __half2float(f1[128]);
                float p20 = __half2float(f2[0]), p21 = __half2float(f2[64]), p22 = __half2float(f2[128]);
                float p30 = __half2float(f3[0]), p31 = __half2float(f3[64]), p32 = __half2float(f3[128]);
                acc0 += v0.y * p00; acc1 += v0.z * p01; acc2 += v0.w * p02;
                acc0 += v1.y * p10; acc1 += v1.z * p11; acc2 += v1.w * p12;
                acc0 += v2.y * p20; acc1 += v2.z * p21; acc2 += v2.w * p22;
                acc0 += v3.y * p30; acc1 += v3.z * p31; acc2 += v3.w * p32;
            }
            for (; t < c; ++t) {
                float4 v = ebuf[t];
                const __half* fr = feat + (size_t)__float_as_int(v.x) * 192 + lane;
                acc0 += v.y * __half2float(fr[0]);
                acc1 += v.z * __half2float(fr[64]);
                acc2 += v.w * __half2float(fr[128]);
            }
        }
        for (int o = 32; o > 0; o >>= 1) {
            da += __shfl_xor(da, o);
            db += __shfl_xor(db, o);
            dc += __shfl_xor(dc, o);
        }
        den0 = da; den1 = db; den2 = dc;
    }

    float v0 = (cnt > 0) ? acc0 / den0 : 0.f;
    float v1 = (cnt > 0) ? acc1 / den1 : 0.f;
    float v2 = (cnt > 0) ? acc2 / den2 : 0.f;
    float hsum = lrelu(v0 + b[lane], ACT_SLOPE)
               + lrelu(v1 + b[64 + lane], ACT_SLOPE)
               + lrelu(v2 + b[128 + lane], ACT_SLOPE);
    hout[wid * 64 + lane] = __float2half(hsum * (1.f / 3.f));
}

// ---------- logits = h @ Wo + bo ----------
__global__ __launch_bounds__(256) void k_out(const __half* __restrict__ h, const float* __restrict__ Wo,
                                             const float* __restrict__ bo, float* __restrict__ out, int N) {
    __shared__ float Hl[32][65];
    __shared__ float Wl[64 * 8];
    int tid = threadIdx.x;
    int n0 = blockIdx.x * 32;
    for (int i = tid; i < 32 * 64; i += 256) {
        int r = i >> 6, k = i & 63;
        Hl[r][k] = (n0 + r < N) ? __half2float(h[(n0 + r) * 64 + k]) : 0.f;
    }
    for (int i = tid; i < 512; i += 256) Wl[i] = Wo[i];
    __syncthreads();
    int r = tid >> 3, c = tid & 7;
    float acc = 0.f;
    for (int k = 0; k < 64; ++k) acc += Hl[r][k] * Wl[k * 8 + c];
    int row = n0 + r;
    if (row < N) out[row * 8 + c] = acc + bo[c];
}

extern "C" void kernel_launch(void* const* d_in, const int* in_sizes, int n_in,
                              void* d_out, int out_size, void* d_ws, size_t ws_size,
                              hipStream_t stream) {
    const float* x  = (const float*)d_in[0];
    const int* src  = (const int*)d_in[1];
    const int* dst  = (const int*)d_in[2];
    const float *W[5], *b[5], *al[5], *ar[5];
    for (int l = 0; l < 5; ++l) {
        W[l]  = (const float*)d_in[3 + l * 4];
        b[l]  = (const float*)d_in[4 + l * 4];
        al[l] = (const float*)d_in[5 + l * 4];
        ar[l] = (const float*)d_in[6 + l * 4];
    }
    const float* Wo = (const float*)d_in[23];
    const float* bo = (const float*)d_in[24];
    float* out = (float*)d_out;

    char* ws = (char*)d_ws;
    auto alloc = [&](size_t bytes) {
        char* p = ws;
        ws += (bytes + 255) & ~size_t(255);
        return p;
    };
    _Float16* feat = (_Float16*)alloc(sizeof(_Float16) * (size_t)N_NODES * 192);
    float* el      = (float*)alloc(sizeof(float) * (size_t)N_NODES * HEADS);
    float* er      = (float*)alloc(sizeof(float) * (size_t)N_NODES * HEADS);
    _Float16* xh   = (_Float16*)alloc(sizeof(_Float16) * (size_t)N_NODES * IN_FEATS);
    _Float16* h0   = (_Float16*)alloc(sizeof(_Float16) * (size_t)N_NODES * 64);
    _Float16* h1   = (_Float16*)alloc(sizeof(_Float16) * (size_t)N_NODES * 64);
    _Float16* wt   = (_Float16*)alloc(sizeof(_Float16) * (24576 + 4 * 12288));
    int* deg    = (int*)alloc(sizeof(int) * N_NODES);
    int* off    = (int*)alloc(sizeof(int) * (N_NODES + 1));
    int* cur    = (int*)alloc(sizeof(int) * N_NODES);
    int* ssrc   = (int*)alloc(sizeof(int) * N_EDGES);
    int* bsum   = (int*)alloc(sizeof(int) * 64);

    const int NB = (N_NODES + 2047) / 2048;   // 25 (<=64 required by k_scan2)
    (void)hipMemsetAsync(deg, 0, sizeof(int) * N_NODES, stream);
    (void)hipMemsetAsync(cur, 0, sizeof(int) * N_NODES, stream);
    k_deg<<<NCHUNK * NGRP, 256, 0, stream>>>(dst, deg, N_EDGES);
    k_scan1<<<NB, 256, 0, stream>>>(deg, off, bsum, N_NODES);
    k_scan2<<<1, 64, 0, stream>>>(bsum, NB);
    k_scan3<<<(N_NODES + 255) / 256, 256, 0, stream>>>(off, bsum, N_NODES, N_EDGES);
    k_fill<<<NCHUNK * NGRP, 256, 0, stream>>>(src, dst, off, cur, ssrc, N_EDGES);
    k_xcast<<<(N_NODES * IN_FEATS / 8 + 255) / 256, 256, 0, stream>>>(x, xh, N_NODES * IN_FEATS / 8);
    k_wcast<<<(24576 + 4 * 12288 + 255) / 256, 256, 0, stream>>>(W[0], W[1], W[2], W[3], W[4], wt);

    const _Float16* hin = xh;
    _Float16* hbuf[2] = {h0, h1};
    const _Float16* wts[5] = {wt, wt + 24576, wt + 24576 + 12288, wt + 24576 + 2 * 12288, wt + 24576 + 3 * 12288};
    int din = IN_FEATS;
    for (int l = 0; l < 5; ++l) {
        int nrt = (N_NODES + 31) / 32;
        k_gemm<<<nrt * 3, 64, 0, stream>>>(hin, wts[l], al[l], ar[l], feat, el, er, N_NODES, din);
        _Float16* hn = hbuf[l & 1];
        k_agg<<<N_NODES, 64, 0, stream>>>(off, ssrc, el, er,
                                          (const __half*)feat, b[l],
                                          (__half*)hn, N_NODES);
        hin = hn;
        din = HID;
    }
    k_out<<<(N_NODES + 31) / 32, 256, 0, stream>>>((const __half*)hin, Wo, bo, out, N_NODES);
}